// Round 3
// baseline (100.209 us; speedup 1.0000x reference)
//
#include <hip/hip_runtime.h>
#include <math.h>

// Problem constants
#define NS1 4096
#define NS2 4096
#define ND  64

// Workspace layout (float offsets)
static constexpr int OFF_SUMX1 = 0;     // 64
static constexpr int OFF_SUMX2 = 64;    // 64
static constexpr int OFF_SSQX2 = 128;   // 64
static constexpr int OFF_SCALE = 192;   // 64
static constexpr int OFF_BETA  = 256;   // 64
static constexpr int OFF_MU    = 320;   // 64
static constexpr int OFF_KB    = 384;   // 2 (||Wk col|| bounds)
static constexpr int OFF_Q     = 512;             // q0[4096], q1[4096]
static constexpr int OFF_KV    = 512 + 2 * 4096;  // float4 kv[4096] = (k0,k1,v0,v1)
static constexpr int OFF_NUM   = OFF_KV + 4 * 4096; // num0[4096], num1[4096]
static constexpr int OFF_DEN   = OFF_NUM + 2 * 4096; // den0[4096], den1[4096]

__device__ inline float wred64(float v) {
    #pragma unroll
    for (int off = 32; off; off >>= 1) v += __shfl_xor(v, off);
    return v;
}

// K1: column sums of x1, column sums + sumsq of x2.
// 256 blocks x 256 threads. Blocks 0..127 -> x1 (32 rows each), 128..255 -> x2.
__global__ __launch_bounds__(256) void k_colred(const float* __restrict__ x1,
                                                const float* __restrict__ x2,
                                                float* __restrict__ ws) {
    int b = blockIdx.x;
    int tid = threadIdx.x;
    int w = tid >> 6, d = tid & 63;
    bool isx2 = (b >= 128);
    const float* x = isx2 ? x2 : x1;
    int row0 = (isx2 ? (b - 128) : b) * 32 + w * 8;
    float s = 0.f, ss = 0.f;
    #pragma unroll
    for (int i = 0; i < 8; ++i) {
        float v = x[(row0 + i) * ND + d];
        s += v; ss += v * v;
    }
    __shared__ float redS[256];
    __shared__ float redQ[256];
    redS[tid] = s; redQ[tid] = ss;
    __syncthreads();
    if (tid < 64) {
        float st = redS[tid] + redS[tid + 64] + redS[tid + 128] + redS[tid + 192];
        if (!isx2) {
            atomicAdd(&ws[OFF_SUMX1 + tid], st);
        } else {
            float sq = redQ[tid] + redQ[tid + 64] + redQ[tid + 128] + redQ[tid + 192];
            atomicAdd(&ws[OFF_SUMX2 + tid], st);
            atomicAdd(&ws[OFF_SSQX2 + tid], sq);
        }
    }
}

// K2: tiny prep — CBN MLPs, scale/beta/mu, k-bounds. 1 block, 64 threads (1 wave).
__global__ __launch_bounds__(64) void k_prep(const float* __restrict__ Wg1,
                                             const float* __restrict__ Wg2,
                                             const float* __restrict__ Wb1,
                                             const float* __restrict__ Wb2,
                                             const float* __restrict__ Wk,
                                             float* __restrict__ ws) {
    int d = threadIdx.x;
    __shared__ float h[64], ag[64], ab[64];
    h[d] = ws[OFF_SUMX1 + d] * (1.f / (float)NS1);
    __syncthreads();
    float tg = 0.f, tb = 0.f;
    #pragma unroll 8
    for (int j = 0; j < 64; ++j) {
        float hj = h[j];
        tg = fmaf(hj, Wg1[j * 64 + d], tg);
        tb = fmaf(hj, Wb1[j * 64 + d], tb);
    }
    ag[d] = fmaxf(tg, 0.f);
    ab[d] = fmaxf(tb, 0.f);
    __syncthreads();
    float dg = 0.f, db = 0.f;
    #pragma unroll 8
    for (int j = 0; j < 64; ++j) {
        dg = fmaf(ag[j], Wg2[j * 64 + d], dg);
        db = fmaf(ab[j], Wb2[j * 64 + d], db);
    }
    float mu = ws[OFF_SUMX2 + d] * (1.f / (float)NS2);
    float var = ws[OFF_SSQX2 + d] * (1.f / (float)NS2) - mu * mu;
    ws[OFF_SCALE + d] = (1.f + dg) * rsqrtf(var + 1e-5f);
    ws[OFF_BETA + d]  = db;
    ws[OFF_MU + d]    = mu;
    // per-head k bound: ||Wk[:,h]||
    float k0 = Wk[d * 2 + 0], k1 = Wk[d * 2 + 1];
    float s0 = wred64(k0 * k0);
    float s1 = wred64(k1 * k1);
    if (d == 0) { ws[OFF_KB + 0] = sqrtf(s0); ws[OFF_KB + 1] = sqrtf(s1); }
}

// K3: per-row L2 norms + BN + tiny projections. One wave per row, lane = column.
// Grid 2048 x 256 (4 rows/block). Blocks 0..1023 -> x2 rows (k,v); 1024..2047 -> x1 rows (q).
__global__ __launch_bounds__(256) void k_proj(const float* __restrict__ x1,
                                              const float* __restrict__ x2,
                                              const float* __restrict__ Wq,
                                              const float* __restrict__ Wk,
                                              const float* __restrict__ Wv,
                                              float* __restrict__ ws) {
    int b = blockIdx.x;
    int w = threadIdx.x >> 6, d = threadIdx.x & 63;
    bool isx1 = (b >= 1024);
    int row = (isx1 ? (b - 1024) : b) * 4 + w;
    if (!isx1) {
        float x = x2[row * ND + d];
        float n2 = wred64(x * x);
        float y = x * (1.f / fmaxf(sqrtf(n2), 1e-12f));      // y2 row
        float vv = fmaf(ws[OFF_SCALE + d], x - ws[OFF_MU + d], ws[OFF_BETA + d]); // v2_0
        float nv = wred64(vv * vv);
        float vn = vv * (1.f / fmaxf(sqrtf(nv), 1e-12f));    // v2n row
        float k0 = wred64(y  * Wk[d * 2 + 0]);
        float k1 = wred64(y  * Wk[d * 2 + 1]);
        float v0 = wred64(vn * Wv[d * 2 + 0]);
        float v1 = wred64(vn * Wv[d * 2 + 1]);
        if (d == 0) {
            ((float4*)(ws + OFF_KV))[row] = make_float4(k0, k1, v0, v1);
        }
    } else {
        float x = x1[row * ND + d];
        float n2 = wred64(x * x);
        float y = x * (1.f / fmaxf(sqrtf(n2), 1e-12f));      // y1 row
        float q0 = wred64(y * Wq[d * 2 + 0]);
        float q1 = wred64(y * Wq[d * 2 + 1]);
        if (d == 0) {
            ws[OFF_Q + row] = q0;
            ws[OFF_Q + NS1 + row] = q1;
        }
    }
}

// K4: attention partial sums. Rank-1 scores: attn[h,s,t] = q[s,h]*k[t,h].
// Grid = 16 s-chunks x 32 t-chunks = 512 blocks, 256 threads (thread = one s).
// t-tile (128 float4) staged in LDS, inner loop is broadcast ds_read_b128.
__global__ __launch_bounds__(256) void k_attn(const float* __restrict__ wsc,
                                              float* __restrict__ ws) {
    __shared__ float4 kv[128];
    int b = blockIdx.x;
    int sc = b & 15, tc = b >> 4;
    int tid = threadIdx.x;
    const float4* kvg = (const float4*)(wsc + OFF_KV);
    if (tid < 128) kv[tid] = kvg[tc * 128 + tid];
    __syncthreads();
    int s = sc * 256 + tid;
    float q0 = wsc[OFF_Q + s];
    float q1 = wsc[OFF_Q + NS1 + s];
    float m0 = fabsf(q0) * wsc[OFF_KB + 0];  // analytic max bound: q*k <= |q|*||Wk col||
    float m1 = fabsf(q1) * wsc[OFF_KB + 1];
    float n0 = 0.f, d0 = 0.f, n1 = 0.f, d1 = 0.f;
    #pragma unroll 4
    for (int i = 0; i < 128; ++i) {
        float4 t = kv[i];
        float e0 = __expf(fmaf(q0, t.x, -m0));
        float e1 = __expf(fmaf(q1, t.y, -m1));
        n0 = fmaf(e0, t.z, n0); d0 += e0;
        n1 = fmaf(e1, t.w, n1); d1 += e1;
    }
    atomicAdd(&ws[OFF_NUM + s],        n0);
    atomicAdd(&ws[OFF_NUM + NS1 + s],  n1);
    atomicAdd(&ws[OFF_DEN + s],        d0);
    atomicAdd(&ws[OFF_DEN + NS1 + s],  d1);
}

// K5: epilogue — out = sigmoid((num/den) @ Wo + bo). 16 blocks x 256 threads.
__global__ __launch_bounds__(256) void k_out(const float* __restrict__ ws,
                                             const float* __restrict__ Wo,
                                             const float* __restrict__ bo,
                                             float* __restrict__ out) {
    int s = blockIdx.x * 256 + threadIdx.x;
    float o0 = ws[OFF_NUM + s]       / ws[OFF_DEN + s];
    float o1 = ws[OFF_NUM + NS1 + s] / ws[OFF_DEN + NS1 + s];
    float z0 = fmaf(o0, Wo[0], fmaf(o1, Wo[2], bo[0]));
    float z1 = fmaf(o0, Wo[1], fmaf(o1, Wo[3], bo[1]));
    out[s * 2 + 0] = 1.f / (1.f + __expf(-z0));
    out[s * 2 + 1] = 1.f / (1.f + __expf(-z1));
}

extern "C" void kernel_launch(void* const* d_in, const int* in_sizes, int n_in,
                              void* d_out, int out_size, void* d_ws, size_t ws_size,
                              hipStream_t stream) {
    const float* x1  = (const float*)d_in[0];
    const float* x2  = (const float*)d_in[1];
    const float* Wq  = (const float*)d_in[2];
    const float* Wk  = (const float*)d_in[3];
    const float* Wv  = (const float*)d_in[4];
    const float* Wo  = (const float*)d_in[5];
    const float* bo  = (const float*)d_in[6];
    const float* Wg1 = (const float*)d_in[7];
    const float* Wg2 = (const float*)d_in[8];
    const float* Wb1 = (const float*)d_in[9];
    const float* Wb2 = (const float*)d_in[10];
    float* ws  = (float*)d_ws;
    float* out = (float*)d_out;

    // Zero the accumulators (ws is poisoned 0xAA before every timed launch).
    hipMemsetAsync((char*)d_ws + OFF_SUMX1 * 4, 0, 512 * 4, stream);           // sums + prep slots
    hipMemsetAsync((char*)d_ws + OFF_NUM * 4,   0, 4 * NS1 * 4, stream);       // num + den

    k_colred<<<256, 256, 0, stream>>>(x1, x2, ws);
    k_prep<<<1, 64, 0, stream>>>(Wg1, Wg2, Wb1, Wb2, Wk, ws);
    k_proj<<<2048, 256, 0, stream>>>(x1, x2, Wq, Wk, Wv, ws);
    k_attn<<<512, 256, 0, stream>>>(ws, ws);
    k_out<<<16, 256, 0, stream>>>(ws, Wo, bo, out);
}